// Round 7
// baseline (332.650 us; speedup 1.0000x reference)
//
#include <hip/hip_runtime.h>
#include <hip/hip_bf16.h>

#define B_   2
#define T_   2048
#define HID_ 2048
#define H_   16
#define KVH_ 4
#define D_   128
#define GQ_  (H_ / KVH_)

#define QN_  8388608   // B*T*H*D
#define KN_  2097152   // B*T*KVH*D

typedef unsigned short u16;
typedef __attribute__((ext_vector_type(8))) unsigned short us8v;
typedef __attribute__((ext_vector_type(8))) short s16x8;   // MFMA A/B frag
typedef __attribute__((ext_vector_type(4))) float f32x4;   // MFMA C/D frag

__device__ __forceinline__ float bf2f(u16 u) {
  return __uint_as_float(((unsigned)u) << 16);
}
__device__ __forceinline__ u16 f2bf(float f) {
  unsigned x = __float_as_uint(f);
  return (u16)((x + 0x7fffu + ((x >> 16) & 1u)) >> 16);  // RNE
}

// global(16B per lane) -> LDS direct, wave-uniform dst base + lane*16.
__device__ __forceinline__ void gl2lds(const void* gp, void* lp) {
  __builtin_amdgcn_global_load_lds(
      (const __attribute__((address_space(1))) unsigned int*)gp,
      (__attribute__((address_space(3))) unsigned int*)lp, 16, 0, 0);
}

// ---------------------------------------------------------------------------
// On-device dtype probe (bf16 vs fp32), per tensor — R7-proven on this
// mixed-dtype input set. Wave-uniform, deterministic, graph-capture safe.
// ---------------------------------------------------------------------------
__device__ __forceinline__ void probe2(const void* A, const void* W, int tid,
                                       bool* abf, bool* wbf) {
  __shared__ int cA, zA, cW, zW;
  if (tid == 0) { cA = 0; zA = 0; cW = 0; zW = 0; }
  __syncthreads();
  const int i = 16384 + tid;
  {
    const u16 raw = ((const u16*)A)[i];
    const float v = bf2f(raw);
    const bool bad = !(fabsf(v) <= 1e6f) ||
                     (v != 0.0f && fabsf(v) < 1e-10f);
    if (bad) atomicAdd(&cA, 1);
    if (((tid & 1) == 0) && raw == 0) atomicAdd(&zA, 1);
  }
  {
    const u16 raw = ((const u16*)W)[i];
    const float v = bf2f(raw);
    const bool bad = !(fabsf(v) <= 1e6f) ||
                     (v != 0.0f && fabsf(v) < 1e-10f);
    if (bad) atomicAdd(&cW, 1);
    if (((tid & 1) == 0) && raw == 0) atomicAdd(&zW, 1);
  }
  __syncthreads();
  *abf = (cA < 8) && (zA < 100);
  *wbf = (cW < 8) && (zW < 100);
}

// ---------------------------------------------------------------------------
// One-time activation convert: x (fp32 OR bf16, probed) -> bf16, vectorized.
// ---------------------------------------------------------------------------
__global__ __launch_bounds__(256) void conv_bf16(const void* __restrict__ in,
                                                 u16* __restrict__ outb,
                                                 int total8) {
  const int tid = threadIdx.x;
  bool ibf, dummy;
  probe2(in, in, tid, &ibf, &dummy);
  const int idx = blockIdx.x * 256 + tid;
  if (idx >= total8) return;
  if (ibf) {
    *(us8v*)&outb[(size_t)idx * 8] = *(const us8v*)((const u16*)in +
                                                    (size_t)idx * 8);
  } else {
    const float4 f0 = *(const float4*)((const float*)in + (size_t)idx * 8);
    const float4 f1 = *(const float4*)((const float*)in + (size_t)idx * 8 + 4);
    uint4 w;
    asm("v_cvt_pk_bf16_f32 %0, %1, %2" : "=v"(w.x) : "v"(f0.x), "v"(f0.y));
    asm("v_cvt_pk_bf16_f32 %0, %1, %2" : "=v"(w.y) : "v"(f0.z), "v"(f0.w));
    asm("v_cvt_pk_bf16_f32 %0, %1, %2" : "=v"(w.z) : "v"(f1.x), "v"(f1.y));
    asm("v_cvt_pk_bf16_f32 %0, %1, %2" : "=v"(w.w) : "v"(f1.z), "v"(f1.w));
    *(uint4*)&outb[(size_t)idx * 8] = w;
  }
}

// ---------------------------------------------------------------------------
// Transpose W[K][N] (bf16 OR fp32, probed) -> WT[N][K] bf16. Runs once per
// weight; makes GEMM B-staging k-contiguous (required by MFMA B-fragment).
// ---------------------------------------------------------------------------
__global__ __launch_bounds__(256) void transp_k(const void* __restrict__ Wv_,
                                                u16* __restrict__ WT,
                                                int K, int N) {
  const int tid = threadIdx.x;
  bool wbf, dummy;
  probe2(Wv_, Wv_, tid, &wbf, &dummy);

  __shared__ float tile[64][65];
  const int kb = blockIdx.y * 64;
  const int nb = blockIdx.x * 64;

  for (int it = tid; it < 512; it += 256) {
    const int r = it >> 3;            // k-row 0..63
    const int g = it & 7;             // n-granule
    const size_t off = (size_t)(kb + r) * N + nb + g * 8;
    float f[8];
    if (wbf) {
      const us8v t8 = *(const us8v*)((const u16*)Wv_ + off);
#pragma unroll
      for (int e = 0; e < 8; ++e) f[e] = bf2f(t8[e]);
    } else {
      const float4 f0 = *(const float4*)((const float*)Wv_ + off);
      const float4 f1 = *(const float4*)((const float*)Wv_ + off + 4);
      f[0] = f0.x; f[1] = f0.y; f[2] = f0.z; f[3] = f0.w;
      f[4] = f1.x; f[5] = f1.y; f[6] = f1.z; f[7] = f1.w;
    }
#pragma unroll
    for (int e = 0; e < 8; ++e) tile[r][g * 8 + e] = f[e];
  }
  __syncthreads();
  for (int it = tid; it < 512; it += 256) {
    const int n = it >> 3;            // 0..63
    const int g = it & 7;             // k-granule
    us8v tmp;
#pragma unroll
    for (int e = 0; e < 8; ++e) tmp[e] = f2bf(tile[g * 8 + e][n]);
    *(us8v*)&WT[(size_t)(nb + n) * K + kb + g * 8] = tmp;
  }
}

// ---------------------------------------------------------------------------
// MFMA GEMM v3: C[M,N] = A[M,K] @ W[K,N]; A bf16 (pre-converted), W
// pre-transposed (WT[N][K] bf16). 128x128 tile, 4 waves (2x2), 4x4
// v_mfma_f32_16x16x32_bf16 per wave, BK=32.
// NEW (T4): 3-BUFFER RING + COUNTED VMCNT. 2-deep prefetch; per K-step:
// issue stage(t+2); compute buf[t]; s_waitcnt vmcnt(4) (retires stage(t+1),
// leaves stage(t+2) IN FLIGHT across the barrier) + raw s_barrier.
// R6's __syncthreads drained vmcnt to 0 every step -> staging latency
// exposed (the documented ~20% barrier-drain stall). Each stage = 4 VMEM
// instructions/wave; tail steps use vmcnt(0) (at 4 outstanding, vmcnt(4)
// would NOT wait). Requires K >= 64 (true: K=2048 both calls).
// LDS linear, granule XOR g^((r>>1)&3) folded into global source (m173);
// fragment reads apply the same involution -> conflict-free ds_read_b128.
// OMODE: 0 = fp32 out row-major.
//        3 = fused QKV epilogue: col<2048 -> qbuf; col<2560 -> kbuf;
//            else -> vT[((b*KVH+kvh)*D+d)*T+t] (V^T for attention PV).
// ---------------------------------------------------------------------------
#define G_STAGE(bi, kk)                                                       \
  do {                                                                        \
    _Pragma("unroll") for (int _p = 0; _p < 2; ++_p) {                        \
      const int _it = tid + _p * 256;                                         \
      const int _r = _it >> 2, _g = _it & 3;                                  \
      const int _gs = _g ^ ((_r >> 1) & 3);                                   \
      gl2lds(Ab + (size_t)(m0 + _r) * K + (kk) + _gs * 8,                     \
             &Alds[bi][((tid & ~63) + _p * 256) * 8]);                        \
    }                                                                         \
    _Pragma("unroll") for (int _p = 0; _p < 2; ++_p) {                        \
      const int _it = tid + _p * 256;                                         \
      const int _n = _it >> 2, _g = _it & 3;                                  \
      const int _gs = _g ^ ((_n >> 1) & 3);                                   \
      gl2lds(WT + (size_t)(n0 + _n) * K + (kk) + _gs * 8,                     \
             &Blds[bi][((tid & ~63) + _p * 256) * 8]);                        \
    }                                                                         \
  } while (0)

template <int OMODE>
__global__ __launch_bounds__(256) void gemm_mfma(const u16* __restrict__ Ab,
                                                 const u16* __restrict__ WT,
                                                 void* __restrict__ Cv,
                                                 int M, int N, int K) {
  const int tid = threadIdx.x;

  __shared__ __align__(16) u16 Alds[3][128 * 32];
  __shared__ __align__(16) u16 Blds[3][128 * 32];

  const int m0 = blockIdx.y * 128;
  const int n0 = blockIdx.x * 128;
  const int wave = tid >> 6;
  const int lane = tid & 63;
  const int wm = (wave >> 1) * 64;
  const int wn = (wave & 1) * 64;
  const int lrow = lane & 15;
  const int lq = lane >> 4;

  f32x4 acc[4][4] = {};

  // Prologue: fill stages 0 and 1; wait only for stage 0 (vmcnt 4 = S1 in
  // flight), then barrier.
  G_STAGE(0, 0);
  G_STAGE(1, 32);
  asm volatile("s_waitcnt vmcnt(4)" ::: "memory");
  __builtin_amdgcn_s_barrier();
  __builtin_amdgcn_sched_barrier(0);

  int cur = 0;
  for (int k0 = 0; k0 < K; k0 += 32) {
    const int nxt = (cur == 2) ? 0 : cur + 1;
    const int nn = (nxt == 2) ? 0 : nxt + 1;
    const bool more = (k0 + 64) < K;
    if (more) G_STAGE(nn, k0 + 64);

    s16x8 af[4], bfr[4];
#pragma unroll
    for (int mi = 0; mi < 4; ++mi) {
      const int row = wm + 16 * mi + lrow;
      af[mi] =
          *(const s16x8*)&Alds[cur][row * 32 + ((lq ^ ((row >> 1) & 3)) * 8)];
    }
#pragma unroll
    for (int ni = 0; ni < 4; ++ni) {
      const int row = wn + 16 * ni + lrow;
      bfr[ni] =
          *(const s16x8*)&Blds[cur][row * 32 + ((lq ^ ((row >> 1) & 3)) * 8)];
    }
    __builtin_amdgcn_s_setprio(1);
#pragma unroll
    for (int mi = 0; mi < 4; ++mi)
#pragma unroll
      for (int ni = 0; ni < 4; ++ni)
        acc[mi][ni] = __builtin_amdgcn_mfma_f32_16x16x32_bf16(
            af[mi], bfr[ni], acc[mi][ni], 0, 0, 0);
    __builtin_amdgcn_s_setprio(0);

    // Counted wait: retire the NEXT buffer's stage, keep the one after in
    // flight. Tail (no new issue): drain fully so the last stage lands.
    if (more)
      asm volatile("s_waitcnt vmcnt(4)" ::: "memory");
    else
      asm volatile("s_waitcnt vmcnt(0)" ::: "memory");
    __builtin_amdgcn_s_barrier();
    __builtin_amdgcn_sched_barrier(0);
    cur = nxt;
  }

  // epilogue: D col=lane&15, row=quad*4+reg
#pragma unroll
  for (int mi = 0; mi < 4; ++mi) {
#pragma unroll
    for (int ni = 0; ni < 4; ++ni) {
      const int row0 = m0 + wm + 16 * mi + lq * 4;
      const int col = n0 + wn + 16 * ni + lrow;
#pragma unroll
      for (int r = 0; r < 4; ++r) {
        const int row = row0 + r;
        if (OMODE == 0) {
          ((float*)Cv)[(size_t)row * N + col] = acc[mi][ni][r];
        } else {
          const u16 val = f2bf(acc[mi][ni][r]);
          if (col < 2048) {
            ((u16*)Cv)[(size_t)row * 2048 + col] = val;           // qbuf
          } else if (col < 2560) {
            ((u16*)Cv)[QN_ + (size_t)row * 512 + (col - 2048)] = val;  // kbuf
          } else {
            const int c = col - 2560;          // 0..511
            const int kvh = c >> 7;
            const int d = c & 127;
            const int bb = row >> 11;          // T_ == 2048
            const int tt = row & (T_ - 1);
            ((u16*)Cv)[QN_ + KN_ +
                       ((size_t)(bb * KVH_ + kvh) * D_ + d) * T_ + tt] = val;
          }
        }
      }
    }
  }
}

// ---------------------------------------------------------------------------
// RoPE (rotate-half), in place on a BF16 (B, T, NH, D) workspace tensor.
// qs: output scale (1/sqrt(D) for Q — folds the attention scale into Q).
// ---------------------------------------------------------------------------
__global__ __launch_bounds__(256) void rope_bf(u16* __restrict__ t,
                                               const void* __restrict__ cosT,
                                               const void* __restrict__ sinT,
                                               int NH, int total, float qs) {
  const int tid = threadIdx.x;
  bool cbf, sbf;
  probe2(cosT, sinT, tid, &cbf, &sbf);

  const int idx = blockIdx.x * blockDim.x + tid;
  if (idx >= total) return;
  const int d = idx & 63;
  const int rest = idx >> 6;
  const int tt = (rest / NH) % T_;
  const size_t base = (size_t)rest * D_;
  const int ci = tt * D_ + d;
  float c1, s1, c2, s2;
  if (cbf) {
    c1 = bf2f(((const u16*)cosT)[ci]);
    c2 = bf2f(((const u16*)cosT)[ci + 64]);
  } else {
    c1 = ((const float*)cosT)[ci];
    c2 = ((const float*)cosT)[ci + 64];
  }
  if (sbf) {
    s1 = bf2f(((const u16*)sinT)[ci]);
    s2 = bf2f(((const u16*)sinT)[ci + 64]);
  } else {
    s1 = ((const float*)sinT)[ci];
    s2 = ((const float*)sinT)[ci + 64];
  }
  const float x1 = bf2f(t[base + d]);
  const float x2 = bf2f(t[base + d + 64]);
  t[base + d] = f2bf((x1 * c1 - x2 * s1) * qs);
  t[base + d + 64] = f2bf((x2 * c2 + x1 * s2) * qs);
}

// ---------------------------------------------------------------------------
// Causal GQA flash attention, MFMA v4 (unchanged from R6, passing):
// swapped QK^T (lane-local softmax), paired q-tiles, 8 waves, dbuf
// global_load_lds staging, defer-max, setprio.
// ---------------------------------------------------------------------------
#define ATT_STAGE(bi, ktile)                                                  \
  do {                                                                        \
    const int _k0 = (ktile) * 64;                                             \
    u16* _bk = &SM[(bi) * 16384];                                             \
    _Pragma("unroll") for (int _p = 0; _p < 2; ++_p) {                        \
      const int _it = tid + _p * 512;                                         \
      const int _r = _it >> 4, _s = _it & 15;                                 \
      gl2lds(kp + (size_t)(_k0 + _r) * (KVH_ * D_) + ((_s ^ (_r & 7)) * 8),   \
             &_bk[((tid & ~63) + _p * 512) * 8]);                             \
    }                                                                         \
    _Pragma("unroll") for (int _p = 0; _p < 2; ++_p) {                        \
      const int _it = tid + _p * 512;                                         \
      const int _r = _it >> 3, _s = _it & 7;                                  \
      gl2lds(vp + (size_t)_r * T_ + _k0 + ((_s ^ (_r & 7)) * 8),              \
             &_bk[8192 + ((tid & ~63) + _p * 512) * 8]);                      \
    }                                                                         \
  } while (0)

__global__ __launch_bounds__(512, 4) void attn_mfma(
    const u16* __restrict__ q, const u16* __restrict__ k,
    const u16* __restrict__ vT, u16* __restrict__ o) {
  const int tid = threadIdx.x;
  const int ip = blockIdx.y;                 // pair index 0..15
  const int bh = blockIdx.x;
  const int b = bh >> 4;
  const int h = bh & 15;
  const int kvh = h >> 2;
  const int hi0 = 64 * (31 - ip);
  const int lo0 = 64 * ip;

  __shared__ __align__(16) u16 SM[2 * 16384];  // dbuf {Ks 64x128, Vt 128x64}
  __shared__ __align__(16) u16 Pl[128 * 64];   // P (bf16), granule-XOR

  const int wave = tid >> 6;                 // 0..7
  const int lane = tid & 63;
  const int l15 = lane & 15;
  const int quad = lane >> 4;
  const bool isHi = wave < 4;
  const int rowbase = isHi ? (hi0 + 16 * wave) : (lo0 + 16 * (wave - 4));
  const int pr0 = 16 * wave;                 // Pl row base, wave-private

  const u16* kp = k + ((size_t)b * T_ * KVH_ + kvh) * D_;
  const u16* vp = vT + (size_t)(b * KVH_ + kvh) * D_ * T_;

  // Q fragment, reg-resident: B-layout [n=q=l15][d=st*32+quad*8+j].
  s16x8 qf[4];
  {
    const size_t qrow = ((size_t)(b * T_ + rowbase + l15) * H_ + h) * D_;
#pragma unroll
    for (int st = 0; st < 4; ++st)
      qf[st] = *(const s16x8*)&q[qrow + st * 32 + quad * 8];
  }

  f32x4 acc_o[8] = {};   // PV out: row q=quad*4+r, col d=nt2*16+l15
  float m_s = -1.0e30f, l_s = 0.0f;   // per-lane state for q = rowbase+l15

  const int nkt = 32 - ip;  // hi tile count; lo active while kt <= ip

  ATT_STAGE(0, 0);
  __syncthreads();

  for (int kt = 0; kt < nkt; ++kt) {
    const int k0 = kt * 64;
    const u16* Ks = &SM[(kt & 1) * 16384];
    const u16* Vt = Ks + 8192;

    if (kt + 1 < nkt) ATT_STAGE((kt + 1) & 1, kt + 1);

    const bool active = isHi || (kt <= ip);  // wave-uniform
    if (active) {
      // ---- swapped QK^T: lane holds S[q=l15][k=nt*16+quad*4+r] ----
      f32x4 accs[4] = {};
      __builtin_amdgcn_s_setprio(1);
#pragma unroll
      for (int st = 0; st < 4; ++st) {
        const int g = st * 4 + quad;
#pragma unroll
        for (int nt = 0; nt < 4; ++nt) {
          const int row = nt * 16 + l15;
          const s16x8 kf =
              *(const s16x8*)&Ks[row * 128 + ((g ^ (row & 7)) << 3)];
          accs[nt] = __builtin_amdgcn_mfma_f32_16x16x32_bf16(kf, qf[st],
                                                             accs[nt], 0, 0,
                                                             0);
        }
      }
      __builtin_amdgcn_s_setprio(0);

      // ---- causal mask: wave-uniform branch, rare ----
      if ((k0 + 63) > rowbase) {
        const int qg = rowbase + l15;
#pragma unroll
        for (int nt = 0; nt < 4; ++nt)
#pragma unroll
          for (int r = 0; r < 4; ++r)
            if (qg < (k0 + nt * 16 + quad * 4 + r)) accs[nt][r] = -1.0e30f;
      }

      // ---- row max: in-lane tree + 2 shfl ----
      float t0 = fmaxf(fmaxf(accs[0][0], accs[0][1]),
                       fmaxf(accs[0][2], accs[0][3]));
      float t1 = fmaxf(fmaxf(accs[1][0], accs[1][1]),
                       fmaxf(accs[1][2], accs[1][3]));
      float t2 = fmaxf(fmaxf(accs[2][0], accs[2][1]),
                       fmaxf(accs[2][2], accs[2][3]));
      float t3 = fmaxf(fmaxf(accs[3][0], accs[3][1]),
                       fmaxf(accs[3][2], accs[3][3]));
      float mx = fmaxf(fmaxf(t0, t1), fmaxf(t2, t3));
      mx = fmaxf(mx, __shfl_xor(mx, 16));
      mx = fmaxf(mx, __shfl_xor(mx, 32));

      // ---- defer-max (T13) ----
      const int defer = __all(mx <= m_s + 8.0f);
      float alv = 1.0f;
      if (!defer) {
        const float mnew = fmaxf(m_s, mx);
        alv = __expf(m_s - mnew);
        m_s = mnew;
      }

      // ---- exp ----
#pragma unroll
      for (int nt = 0; nt < 4; ++nt)
#pragma unroll
        for (int r = 0; r < 4; ++r)
          accs[nt][r] = __expf(accs[nt][r] - m_s);

      // ---- pack + write P early (ds latency overlaps the sum) ----
#pragma unroll
      for (int nt = 0; nt < 4; ++nt) {
        uint2 w;
        asm("v_cvt_pk_bf16_f32 %0, %1, %2"
            : "=v"(w.x) : "v"(accs[nt][0]), "v"(accs[nt][1]));
        asm("v_cvt_pk_bf16_f32 %0, %1, %2"
            : "=v"(w.y) : "v"(accs[nt][2]), "v"(accs[nt][3]));
        const int prow = pr0 + l15;
        const int c0 = nt * 16 + quad * 4;
        *(uint2*)&Pl[prow * 64 + (((c0 >> 3) ^ (prow & 7)) << 3) + (c0 & 7)] =
            w;
      }

      // ---- row sum + state update ----
      float s0 = (accs[0][0] + accs[0][1]) + (accs[0][2] + accs[0][3]);
      float s1 = (accs[1][0] + accs[1][1]) + (accs[1][2] + accs[1][3]);
      float s2 = (accs[2][0] + accs[2][1]) + (accs[2][2] + accs[2][3]);
      float s3 = (accs[3][0] + accs[3][1]) + (accs[3][2] + accs[3][3]);
      float rs = (s0 + s1) + (s2 + s3);
      rs += __shfl_xor(rs, 16);
      rs += __shfl_xor(rs, 32);
      l_s = l_s * alv + rs;

      // ---- O rescale (only when max grew; al redistributed to PV rows) ----
      if (!defer) {
#pragma unroll
        for (int r = 0; r < 4; ++r) {
          const float a4 = __shfl(alv, 4 * quad + r);
#pragma unroll
          for (int nt2 = 0; nt2 < 8; ++nt2) acc_o[nt2][r] *= a4;
        }
      }

      asm volatile("s_waitcnt lgkmcnt(0)" ::: "memory");
      __builtin_amdgcn_sched_barrier(0);

      // ---- PV: O[16q x 128d] += P[16x64] @ V[64x128] ----
      s16x8 pa[2];
#pragma unroll
      for (int ks = 0; ks < 2; ++ks) {
        const int row = pr0 + l15;
        const int g = ks * 4 + quad;
        pa[ks] = *(const s16x8*)&Pl[row * 64 + ((g ^ (row & 7)) << 3)];
      }
      __builtin_amdgcn_s_setprio(1);
#pragma unroll
      for (int ks = 0; ks < 2; ++ks) {
        const int g = ks * 4 + quad;
#pragma unroll
        for (int nt2 = 0; nt2 < 8; ++nt2) {
          const int row = nt2 * 16 + l15;
          const s16x8 vf =
              *(const s16x8*)&Vt[row * 64 + ((g ^ (row & 7)) << 3)];
          acc_o[nt2] = __builtin_amdgcn_mfma_f32_16x16x32_bf16(pa[ks], vf,
                                                               acc_o[nt2], 0,
                                                               0, 0);
        }
      }
      __builtin_amdgcn_s_setprio(0);
    }

    __syncthreads();  // drains vmcnt: buf^1 staged; all LDS reads retired
  }

  // ---- epilogue: normalize + store (linv redistributed to PV rows) ----
  const float inv = 1.0f / l_s;
#pragma unroll
  for (int r = 0; r < 4; ++r) {
    const float linv = __shfl(inv, 4 * quad + r);
    const size_t orow =
        ((size_t)(b * T_ + rowbase + quad * 4 + r) * H_ + h) * D_;
#pragma unroll
    for (int nt2 = 0; nt2 < 8; ++nt2)
      o[orow + nt2 * 16 + l15] = f2bf(acc_o[nt2][r] * linv);
  }
}

// Fallback: zero d_out (fp32) so an undersized workspace fails cleanly.
__global__ void zero_out_k(float* __restrict__ out, int n) {
  const int i = blockIdx.x * blockDim.x + threadIdx.x;
  if (i < n) out[i] = 0.0f;
}

// ---------------------------------------------------------------------------
extern "C" void kernel_launch(void* const* d_in, const int* in_sizes, int n_in,
                              void* d_out, int out_size, void* d_ws,
                              size_t ws_size, hipStream_t stream) {
  const void* x    = d_in[0];
  const void* cosT = d_in[1];
  const void* sinT = d_in[2];
  const void* Wq   = d_in[3];
  const void* Wk   = d_in[4];
  const void* Wv   = d_in[5];
  const void* Wo   = d_in[6];
  float* out = (float*)d_out;

  // Workspace (bf16 elems): qbuf QN | kbuf KN | vbufT KN | obuf QN |
  //   WqT 4194304 | WkT 1048576 | WvT 1048576 | WoT 4194304  = 60 MiB.
  // xb (bf16 copy of x, QN elems) ALIASES obuf: x is consumed by the QKV
  // GEMM, which completes before attention writes obuf (stream-ordered).
  const size_t QN = QN_;
  const size_t KN = KN_;
  const size_t WQT = (size_t)HID_ * (H_ * D_);     // 4194304
  const size_t WKT = (size_t)HID_ * (KVH_ * D_);   // 1048576
  const size_t need = (2 * QN + 2 * KN + 2 * WQT + 2 * WKT) * sizeof(u16);
  if (ws_size < need) {
    zero_out_k<<<(out_size + 255) / 256, 256, 0, stream>>>(out, out_size);
    return;
  }

  u16* qbuf  = (u16*)d_ws;
  u16* kbuf  = qbuf + QN;
  u16* vbufT = kbuf + KN;    // V^T: [b][kvh][d][t]
  u16* obuf  = vbufT + KN;
  u16* xb    = obuf;         // alias (see above)
  u16* WqT   = obuf + QN;    // WqT|WkT|WvT contiguous => fused-QKV WT[3072][K]
  u16* WkT   = WqT + WQT;
  u16* WvT   = WkT + WKT;
  u16* WoT   = WvT + WKT;

  const int M = B_ * T_;  // 4096
  dim3 blk(256);

  // One-time weight transposes (W[K][N] -> WT[N][K] bf16).
  transp_k<<<dim3((H_ * D_) / 64, HID_ / 64), blk, 0, stream>>>(
      Wq, WqT, HID_, H_ * D_);
  transp_k<<<dim3((KVH_ * D_) / 64, HID_ / 64), blk, 0, stream>>>(
      Wk, WkT, HID_, KVH_ * D_);
  transp_k<<<dim3((KVH_ * D_) / 64, HID_ / 64), blk, 0, stream>>>(
      Wv, WvT, HID_, KVH_ * D_);
  transp_k<<<dim3(HID_ / 64, (H_ * D_) / 64), blk, 0, stream>>>(
      Wo, WoT, H_ * D_, HID_);

  // Activation convert: x -> bf16 (xb), one pass.
  conv_bf16<<<(int)(QN / 8 / 256), blk, 0, stream>>>(x, xb, (int)(QN / 8));

  // Fused QKV projection: N = 2048(Q) + 512(K) + 512(V^T), one GEMM.
  gemm_mfma<3><<<dim3(3072 / 128, M / 128), blk, 0, stream>>>(
      xb, WqT, qbuf, M, 3072, HID_);

  // RoPE. Q additionally pre-scaled by 1/sqrt(D) (folds attn scale).
  const int totq = B_ * T_ * H_ * (D_ / 2);   // 4194304
  rope_bf<<<totq / 256, blk, 0, stream>>>(qbuf, cosT, sinT, H_, totq,
                                          0.08838834764831845f);
  const int totk = B_ * T_ * KVH_ * (D_ / 2); // 1048576
  rope_bf<<<totk / 256, blk, 0, stream>>>(kbuf, cosT, sinT, KVH_, totk, 1.0f);

  // MFMA flash attention v4 (swapped QK^T, lane-local softmax).
  attn_mfma<<<dim3(B_ * H_, 16), dim3(512), 0, stream>>>(
      qbuf, kbuf, vbufT, obuf);

  // Output projection (MFMA, fp32 out).
  gemm_mfma<0><<<dim3(HID_ / 128, M / 128), blk, 0, stream>>>(
      obuf, WoT, out, M, HID_, H_ * D_);
}

// Round 8
// 330.468 us; speedup vs baseline: 1.0066x; 1.0066x over previous
//
#include <hip/hip_runtime.h>
#include <hip/hip_bf16.h>

#define B_   2
#define T_   2048
#define HID_ 2048
#define H_   16
#define KVH_ 4
#define D_   128
#define GQ_  (H_ / KVH_)

#define QN_  8388608   // B*T*H*D
#define KN_  2097152   // B*T*KVH*D

typedef unsigned short u16;
typedef __attribute__((ext_vector_type(8))) unsigned short us8v;
typedef __attribute__((ext_vector_type(8))) short s16x8;   // MFMA A/B frag
typedef __attribute__((ext_vector_type(4))) float f32x4;   // MFMA C/D frag

__device__ __forceinline__ float bf2f(u16 u) {
  return __uint_as_float(((unsigned)u) << 16);
}
__device__ __forceinline__ u16 f2bf(float f) {
  unsigned x = __float_as_uint(f);
  return (u16)((x + 0x7fffu + ((x >> 16) & 1u)) >> 16);  // RNE
}

// global(16B per lane) -> LDS direct, wave-uniform dst base + lane*16.
__device__ __forceinline__ void gl2lds(const void* gp, void* lp) {
  __builtin_amdgcn_global_load_lds(
      (const __attribute__((address_space(1))) unsigned int*)gp,
      (__attribute__((address_space(3))) unsigned int*)lp, 16, 0, 0);
}

// ---------------------------------------------------------------------------
// On-device dtype probe (bf16 vs fp32), per tensor — R7-proven on this
// mixed-dtype input set. Wave-uniform, deterministic, graph-capture safe.
// ---------------------------------------------------------------------------
__device__ __forceinline__ void probe2(const void* A, const void* W, int tid,
                                       bool* abf, bool* wbf) {
  __shared__ int cA, zA, cW, zW;
  if (tid == 0) { cA = 0; zA = 0; cW = 0; zW = 0; }
  __syncthreads();
  const int i = 16384 + tid;
  {
    const u16 raw = ((const u16*)A)[i];
    const float v = bf2f(raw);
    const bool bad = !(fabsf(v) <= 1e6f) ||
                     (v != 0.0f && fabsf(v) < 1e-10f);
    if (bad) atomicAdd(&cA, 1);
    if (((tid & 1) == 0) && raw == 0) atomicAdd(&zA, 1);
  }
  {
    const u16 raw = ((const u16*)W)[i];
    const float v = bf2f(raw);
    const bool bad = !(fabsf(v) <= 1e6f) ||
                     (v != 0.0f && fabsf(v) < 1e-10f);
    if (bad) atomicAdd(&cW, 1);
    if (((tid & 1) == 0) && raw == 0) atomicAdd(&zW, 1);
  }
  __syncthreads();
  *abf = (cA < 8) && (zA < 100);
  *wbf = (cW < 8) && (zW < 100);
}

// ---------------------------------------------------------------------------
// One-time activation convert: x (fp32 OR bf16, probed) -> bf16, vectorized.
// ---------------------------------------------------------------------------
__global__ __launch_bounds__(256) void conv_bf16(const void* __restrict__ in,
                                                 u16* __restrict__ outb,
                                                 int total8) {
  const int tid = threadIdx.x;
  bool ibf, dummy;
  probe2(in, in, tid, &ibf, &dummy);
  const int idx = blockIdx.x * 256 + tid;
  if (idx >= total8) return;
  if (ibf) {
    *(us8v*)&outb[(size_t)idx * 8] = *(const us8v*)((const u16*)in +
                                                    (size_t)idx * 8);
  } else {
    const float4 f0 = *(const float4*)((const float*)in + (size_t)idx * 8);
    const float4 f1 = *(const float4*)((const float*)in + (size_t)idx * 8 + 4);
    uint4 w;
    asm("v_cvt_pk_bf16_f32 %0, %1, %2" : "=v"(w.x) : "v"(f0.x), "v"(f0.y));
    asm("v_cvt_pk_bf16_f32 %0, %1, %2" : "=v"(w.y) : "v"(f0.z), "v"(f0.w));
    asm("v_cvt_pk_bf16_f32 %0, %1, %2" : "=v"(w.z) : "v"(f1.x), "v"(f1.y));
    asm("v_cvt_pk_bf16_f32 %0, %1, %2" : "=v"(w.w) : "v"(f1.z), "v"(f1.w));
    *(uint4*)&outb[(size_t)idx * 8] = w;
  }
}

// ---------------------------------------------------------------------------
// Transpose W[K][N] (bf16 OR fp32, probed) -> WT[N][K] bf16. Runs once per
// weight; makes GEMM B-staging k-contiguous (required by MFMA B-fragment).
// ---------------------------------------------------------------------------
__global__ __launch_bounds__(256) void transp_k(const void* __restrict__ Wv_,
                                                u16* __restrict__ WT,
                                                int K, int N) {
  const int tid = threadIdx.x;
  bool wbf, dummy;
  probe2(Wv_, Wv_, tid, &wbf, &dummy);

  __shared__ float tile[64][65];
  const int kb = blockIdx.y * 64;
  const int nb = blockIdx.x * 64;

  for (int it = tid; it < 512; it += 256) {
    const int r = it >> 3;            // k-row 0..63
    const int g = it & 7;             // n-granule
    const size_t off = (size_t)(kb + r) * N + nb + g * 8;
    float f[8];
    if (wbf) {
      const us8v t8 = *(const us8v*)((const u16*)Wv_ + off);
#pragma unroll
      for (int e = 0; e < 8; ++e) f[e] = bf2f(t8[e]);
    } else {
      const float4 f0 = *(const float4*)((const float*)Wv_ + off);
      const float4 f1 = *(const float4*)((const float*)Wv_ + off + 4);
      f[0] = f0.x; f[1] = f0.y; f[2] = f0.z; f[3] = f0.w;
      f[4] = f1.x; f[5] = f1.y; f[6] = f1.z; f[7] = f1.w;
    }
#pragma unroll
    for (int e = 0; e < 8; ++e) tile[r][g * 8 + e] = f[e];
  }
  __syncthreads();
  for (int it = tid; it < 512; it += 256) {
    const int n = it >> 3;            // 0..63
    const int g = it & 7;             // k-granule
    us8v tmp;
#pragma unroll
    for (int e = 0; e < 8; ++e) tmp[e] = f2bf(tile[g * 8 + e][n]);
    *(us8v*)&WT[(size_t)(nb + n) * K + kb + g * 8] = tmp;
  }
}

// ---------------------------------------------------------------------------
// MFMA GEMM v4: C[M,N] = A[M,K] @ W[K,N]; A bf16 (pre-converted), W
// pre-transposed (WT[N][K] bf16). 128x128 tile, BK=32.
// NEW: 8 WAVES (512 thr), wave grid 2Mx4N -> each wave 64x32 out (4x2
// frags, 8 MFMA + 6 ds_read per step). R7 post-mortem: counted vmcnt was
// a no-op because the limiter is TLP starvation (12 waves/CU, grid-fixed
// 3 blocks/CU; per-step wall 2840cyc >> pipe demand ~1k). 8 waves/block
// doubles resident waves to 24/CU (6/SIMD) at unchanged grid, and halves
// each wave's serial chain.
// 3-buffer ring, 2-deep prefetch, counted vmcnt(2) (stage = 2 VMEM
// instr/thread: 1 A + 1 B). LDS 48KB -> 3 blocks/CU intact.
// LDS linear, granule XOR g^((r>>1)&3) folded into global source (m173);
// fragment reads apply the same involution -> conflict-free ds_read_b128.
// OMODE: 0 = fp32 out row-major.
//        3 = fused QKV epilogue: col<2048 -> qbuf; col<2560 -> kbuf;
//            else -> vT[((b*KVH+kvh)*D+d)*T+t] (V^T for attention PV).
// ---------------------------------------------------------------------------
#define G_STAGE(bi, kk)                                                       \
  do {                                                                        \
    {                                                                         \
      const int _r = tid >> 2, _g = tid & 3;                                  \
      const int _gs = _g ^ ((_r >> 1) & 3);                                   \
      gl2lds(Ab + (size_t)(m0 + _r) * K + (kk) + _gs * 8,                     \
             &Alds[bi][(tid & ~63) * 8]);                                     \
      gl2lds(WT + (size_t)(n0 + _r) * K + (kk) + _gs * 8,                     \
             &Blds[bi][(tid & ~63) * 8]);                                     \
    }                                                                         \
  } while (0)

template <int OMODE>
__global__ __launch_bounds__(512) void gemm_mfma(const u16* __restrict__ Ab,
                                                 const u16* __restrict__ WT,
                                                 void* __restrict__ Cv,
                                                 int M, int N, int K) {
  const int tid = threadIdx.x;

  __shared__ __align__(16) u16 Alds[3][128 * 32];
  __shared__ __align__(16) u16 Blds[3][128 * 32];

  const int m0 = blockIdx.y * 128;
  const int n0 = blockIdx.x * 128;
  const int wave = tid >> 6;               // 0..7
  const int lane = tid & 63;
  const int wm = (wave >> 2) * 64;         // 2 m-halves
  const int wn = (wave & 3) * 32;          // 4 n-quarters
  const int lrow = lane & 15;
  const int lq = lane >> 4;

  f32x4 acc[4][2] = {};

  // Prologue: fill stages 0 and 1; wait only for stage 0 (vmcnt 2 = S1's
  // two loads in flight), then barrier.
  G_STAGE(0, 0);
  G_STAGE(1, 32);
  asm volatile("s_waitcnt vmcnt(2)" ::: "memory");
  __builtin_amdgcn_s_barrier();
  __builtin_amdgcn_sched_barrier(0);

  int cur = 0;
  for (int k0 = 0; k0 < K; k0 += 32) {
    const int nxt = (cur == 2) ? 0 : cur + 1;
    const int nn = (nxt == 2) ? 0 : nxt + 1;
    const bool more = (k0 + 64) < K;
    if (more) G_STAGE(nn, k0 + 64);

    s16x8 af[4], bfr[2];
#pragma unroll
    for (int mi = 0; mi < 4; ++mi) {
      const int row = wm + 16 * mi + lrow;
      af[mi] =
          *(const s16x8*)&Alds[cur][row * 32 + ((lq ^ ((row >> 1) & 3)) * 8)];
    }
#pragma unroll
    for (int ni = 0; ni < 2; ++ni) {
      const int row = wn + 16 * ni + lrow;
      bfr[ni] =
          *(const s16x8*)&Blds[cur][row * 32 + ((lq ^ ((row >> 1) & 3)) * 8)];
    }
    __builtin_amdgcn_s_setprio(1);
#pragma unroll
    for (int mi = 0; mi < 4; ++mi)
#pragma unroll
      for (int ni = 0; ni < 2; ++ni)
        acc[mi][ni] = __builtin_amdgcn_mfma_f32_16x16x32_bf16(
            af[mi], bfr[ni], acc[mi][ni], 0, 0, 0);
    __builtin_amdgcn_s_setprio(0);

    // Counted wait: retire the NEXT buffer's stage (2 instr), keep the one
    // after in flight. Tail: drain fully so the last stage lands.
    if (more)
      asm volatile("s_waitcnt vmcnt(2)" ::: "memory");
    else
      asm volatile("s_waitcnt vmcnt(0)" ::: "memory");
    __builtin_amdgcn_s_barrier();
    __builtin_amdgcn_sched_barrier(0);
    cur = nxt;
  }

  // epilogue: D col=lane&15, row=quad*4+reg
#pragma unroll
  for (int mi = 0; mi < 4; ++mi) {
#pragma unroll
    for (int ni = 0; ni < 2; ++ni) {
      const int row0 = m0 + wm + 16 * mi + lq * 4;
      const int col = n0 + wn + 16 * ni + lrow;
#pragma unroll
      for (int r = 0; r < 4; ++r) {
        const int row = row0 + r;
        if (OMODE == 0) {
          ((float*)Cv)[(size_t)row * N + col] = acc[mi][ni][r];
        } else {
          const u16 val = f2bf(acc[mi][ni][r]);
          if (col < 2048) {
            ((u16*)Cv)[(size_t)row * 2048 + col] = val;           // qbuf
          } else if (col < 2560) {
            ((u16*)Cv)[QN_ + (size_t)row * 512 + (col - 2048)] = val;  // kbuf
          } else {
            const int c = col - 2560;          // 0..511
            const int kvh = c >> 7;
            const int d = c & 127;
            const int bb = row >> 11;          // T_ == 2048
            const int tt = row & (T_ - 1);
            ((u16*)Cv)[QN_ + KN_ +
                       ((size_t)(bb * KVH_ + kvh) * D_ + d) * T_ + tt] = val;
          }
        }
      }
    }
  }
}

// ---------------------------------------------------------------------------
// RoPE (rotate-half), in place on a BF16 (B, T, NH, D) workspace tensor.
// qs: output scale (1/sqrt(D) for Q — folds the attention scale into Q).
// ---------------------------------------------------------------------------
__global__ __launch_bounds__(256) void rope_bf(u16* __restrict__ t,
                                               const void* __restrict__ cosT,
                                               const void* __restrict__ sinT,
                                               int NH, int total, float qs) {
  const int tid = threadIdx.x;
  bool cbf, sbf;
  probe2(cosT, sinT, tid, &cbf, &sbf);

  const int idx = blockIdx.x * blockDim.x + tid;
  if (idx >= total) return;
  const int d = idx & 63;
  const int rest = idx >> 6;
  const int tt = (rest / NH) % T_;
  const size_t base = (size_t)rest * D_;
  const int ci = tt * D_ + d;
  float c1, s1, c2, s2;
  if (cbf) {
    c1 = bf2f(((const u16*)cosT)[ci]);
    c2 = bf2f(((const u16*)cosT)[ci + 64]);
  } else {
    c1 = ((const float*)cosT)[ci];
    c2 = ((const float*)cosT)[ci + 64];
  }
  if (sbf) {
    s1 = bf2f(((const u16*)sinT)[ci]);
    s2 = bf2f(((const u16*)sinT)[ci + 64]);
  } else {
    s1 = ((const float*)sinT)[ci];
    s2 = ((const float*)sinT)[ci + 64];
  }
  const float x1 = bf2f(t[base + d]);
  const float x2 = bf2f(t[base + d + 64]);
  t[base + d] = f2bf((x1 * c1 - x2 * s1) * qs);
  t[base + d + 64] = f2bf((x2 * c2 + x1 * s2) * qs);
}

// ---------------------------------------------------------------------------
// Causal GQA flash attention, MFMA v4 (unchanged, passing):
// swapped QK^T (lane-local softmax), paired q-tiles, 8 waves, dbuf
// global_load_lds staging, defer-max, setprio.
// ---------------------------------------------------------------------------
#define ATT_STAGE(bi, ktile)                                                  \
  do {                                                                        \
    const int _k0 = (ktile) * 64;                                             \
    u16* _bk = &SM[(bi) * 16384];                                             \
    _Pragma("unroll") for (int _p = 0; _p < 2; ++_p) {                        \
      const int _it = tid + _p * 512;                                         \
      const int _r = _it >> 4, _s = _it & 15;                                 \
      gl2lds(kp + (size_t)(_k0 + _r) * (KVH_ * D_) + ((_s ^ (_r & 7)) * 8),   \
             &_bk[((tid & ~63) + _p * 512) * 8]);                             \
    }                                                                         \
    _Pragma("unroll") for (int _p = 0; _p < 2; ++_p) {                        \
      const int _it = tid + _p * 512;                                         \
      const int _r = _it >> 3, _s = _it & 7;                                  \
      gl2lds(vp + (size_t)_r * T_ + _k0 + ((_s ^ (_r & 7)) * 8),              \
             &_bk[8192 + ((tid & ~63) + _p * 512) * 8]);                      \
    }                                                                         \
  } while (0)

__global__ __launch_bounds__(512, 4) void attn_mfma(
    const u16* __restrict__ q, const u16* __restrict__ k,
    const u16* __restrict__ vT, u16* __restrict__ o) {
  const int tid = threadIdx.x;
  const int ip = blockIdx.y;                 // pair index 0..15
  const int bh = blockIdx.x;
  const int b = bh >> 4;
  const int h = bh & 15;
  const int kvh = h >> 2;
  const int hi0 = 64 * (31 - ip);
  const int lo0 = 64 * ip;

  __shared__ __align__(16) u16 SM[2 * 16384];  // dbuf {Ks 64x128, Vt 128x64}
  __shared__ __align__(16) u16 Pl[128 * 64];   // P (bf16), granule-XOR

  const int wave = tid >> 6;                 // 0..7
  const int lane = tid & 63;
  const int l15 = lane & 15;
  const int quad = lane >> 4;
  const bool isHi = wave < 4;
  const int rowbase = isHi ? (hi0 + 16 * wave) : (lo0 + 16 * (wave - 4));
  const int pr0 = 16 * wave;                 // Pl row base, wave-private

  const u16* kp = k + ((size_t)b * T_ * KVH_ + kvh) * D_;
  const u16* vp = vT + (size_t)(b * KVH_ + kvh) * D_ * T_;

  // Q fragment, reg-resident: B-layout [n=q=l15][d=st*32+quad*8+j].
  s16x8 qf[4];
  {
    const size_t qrow = ((size_t)(b * T_ + rowbase + l15) * H_ + h) * D_;
#pragma unroll
    for (int st = 0; st < 4; ++st)
      qf[st] = *(const s16x8*)&q[qrow + st * 32 + quad * 8];
  }

  f32x4 acc_o[8] = {};   // PV out: row q=quad*4+r, col d=nt2*16+l15
  float m_s = -1.0e30f, l_s = 0.0f;   // per-lane state for q = rowbase+l15

  const int nkt = 32 - ip;  // hi tile count; lo active while kt <= ip

  ATT_STAGE(0, 0);
  __syncthreads();

  for (int kt = 0; kt < nkt; ++kt) {
    const int k0 = kt * 64;
    const u16* Ks = &SM[(kt & 1) * 16384];
    const u16* Vt = Ks + 8192;

    if (kt + 1 < nkt) ATT_STAGE((kt + 1) & 1, kt + 1);

    const bool active = isHi || (kt <= ip);  // wave-uniform
    if (active) {
      // ---- swapped QK^T: lane holds S[q=l15][k=nt*16+quad*4+r] ----
      f32x4 accs[4] = {};
      __builtin_amdgcn_s_setprio(1);
#pragma unroll
      for (int st = 0; st < 4; ++st) {
        const int g = st * 4 + quad;
#pragma unroll
        for (int nt = 0; nt < 4; ++nt) {
          const int row = nt * 16 + l15;
          const s16x8 kf =
              *(const s16x8*)&Ks[row * 128 + ((g ^ (row & 7)) << 3)];
          accs[nt] = __builtin_amdgcn_mfma_f32_16x16x32_bf16(kf, qf[st],
                                                             accs[nt], 0, 0,
                                                             0);
        }
      }
      __builtin_amdgcn_s_setprio(0);

      // ---- causal mask: wave-uniform branch, rare ----
      if ((k0 + 63) > rowbase) {
        const int qg = rowbase + l15;
#pragma unroll
        for (int nt = 0; nt < 4; ++nt)
#pragma unroll
          for (int r = 0; r < 4; ++r)
            if (qg < (k0 + nt * 16 + quad * 4 + r)) accs[nt][r] = -1.0e30f;
      }

      // ---- row max: in-lane tree + 2 shfl ----
      float t0 = fmaxf(fmaxf(accs[0][0], accs[0][1]),
                       fmaxf(accs[0][2], accs[0][3]));
      float t1 = fmaxf(fmaxf(accs[1][0], accs[1][1]),
                       fmaxf(accs[1][2], accs[1][3]));
      float t2 = fmaxf(fmaxf(accs[2][0], accs[2][1]),
                       fmaxf(accs[2][2], accs[2][3]));
      float t3 = fmaxf(fmaxf(accs[3][0], accs[3][1]),
                       fmaxf(accs[3][2], accs[3][3]));
      float mx = fmaxf(fmaxf(t0, t1), fmaxf(t2, t3));
      mx = fmaxf(mx, __shfl_xor(mx, 16));
      mx = fmaxf(mx, __shfl_xor(mx, 32));

      // ---- defer-max (T13) ----
      const int defer = __all(mx <= m_s + 8.0f);
      float alv = 1.0f;
      if (!defer) {
        const float mnew = fmaxf(m_s, mx);
        alv = __expf(m_s - mnew);
        m_s = mnew;
      }

      // ---- exp ----
#pragma unroll
      for (int nt = 0; nt < 4; ++nt)
#pragma unroll
        for (int r = 0; r < 4; ++r)
          accs[nt][r] = __expf(accs[nt][r] - m_s);

      // ---- pack + write P early (ds latency overlaps the sum) ----
#pragma unroll
      for (int nt = 0; nt < 4; ++nt) {
        uint2 w;
        asm("v_cvt_pk_bf16_f32 %0, %1, %2"
            : "=v"(w.x) : "v"(accs[nt][0]), "v"(accs[nt][1]));
        asm("v_cvt_pk_bf16_f32 %0, %1, %2"
            : "=v"(w.y) : "v"(accs[nt][2]), "v"(accs[nt][3]));
        const int prow = pr0 + l15;
        const int c0 = nt * 16 + quad * 4;
        *(uint2*)&Pl[prow * 64 + (((c0 >> 3) ^ (prow & 7)) << 3) + (c0 & 7)] =
            w;
      }

      // ---- row sum + state update ----
      float s0 = (accs[0][0] + accs[0][1]) + (accs[0][2] + accs[0][3]);
      float s1 = (accs[1][0] + accs[1][1]) + (accs[1][2] + accs[1][3]);
      float s2 = (accs[2][0] + accs[2][1]) + (accs[2][2] + accs[2][3]);
      float s3 = (accs[3][0] + accs[3][1]) + (accs[3][2] + accs[3][3]);
      float rs = (s0 + s1) + (s2 + s3);
      rs += __shfl_xor(rs, 16);
      rs += __shfl_xor(rs, 32);
      l_s = l_s * alv + rs;

      // ---- O rescale (only when max grew; al redistributed to PV rows) ----
      if (!defer) {
#pragma unroll
        for (int r = 0; r < 4; ++r) {
          const float a4 = __shfl(alv, 4 * quad + r);
#pragma unroll
          for (int nt2 = 0; nt2 < 8; ++nt2) acc_o[nt2][r] *= a4;
        }
      }

      asm volatile("s_waitcnt lgkmcnt(0)" ::: "memory");
      __builtin_amdgcn_sched_barrier(0);

      // ---- PV: O[16q x 128d] += P[16x64] @ V[64x128] ----
      s16x8 pa[2];
#pragma unroll
      for (int ks = 0; ks < 2; ++ks) {
        const int row = pr0 + l15;
        const int g = ks * 4 + quad;
        pa[ks] = *(const s16x8*)&Pl[row * 64 + ((g ^ (row & 7)) << 3)];
      }
      __builtin_amdgcn_s_setprio(1);
#pragma unroll
      for (int ks = 0; ks < 2; ++ks) {
        const int g = ks * 4 + quad;
#pragma unroll
        for (int nt2 = 0; nt2 < 8; ++nt2) {
          const int row = nt2 * 16 + l15;
          const s16x8 vf =
              *(const s16x8*)&Vt[row * 64 + ((g ^ (row & 7)) << 3)];
          acc_o[nt2] = __builtin_amdgcn_mfma_f32_16x16x32_bf16(pa[ks], vf,
                                                               acc_o[nt2], 0,
                                                               0, 0);
        }
      }
      __builtin_amdgcn_s_setprio(0);
    }

    __syncthreads();  // drains vmcnt: buf^1 staged; all LDS reads retired
  }

  // ---- epilogue: normalize + store (linv redistributed to PV rows) ----
  const float inv = 1.0f / l_s;
#pragma unroll
  for (int r = 0; r < 4; ++r) {
    const float linv = __shfl(inv, 4 * quad + r);
    const size_t orow =
        ((size_t)(b * T_ + rowbase + quad * 4 + r) * H_ + h) * D_;
#pragma unroll
    for (int nt2 = 0; nt2 < 8; ++nt2)
      o[orow + nt2 * 16 + l15] = f2bf(acc_o[nt2][r] * linv);
  }
}

// Fallback: zero d_out (fp32) so an undersized workspace fails cleanly.
__global__ void zero_out_k(float* __restrict__ out, int n) {
  const int i = blockIdx.x * blockDim.x + threadIdx.x;
  if (i < n) out[i] = 0.0f;
}

// ---------------------------------------------------------------------------
extern "C" void kernel_launch(void* const* d_in, const int* in_sizes, int n_in,
                              void* d_out, int out_size, void* d_ws,
                              size_t ws_size, hipStream_t stream) {
  const void* x    = d_in[0];
  const void* cosT = d_in[1];
  const void* sinT = d_in[2];
  const void* Wq   = d_in[3];
  const void* Wk   = d_in[4];
  const void* Wv   = d_in[5];
  const void* Wo   = d_in[6];
  float* out = (float*)d_out;

  // Workspace (bf16 elems): qbuf QN | kbuf KN | vbufT KN | obuf QN |
  //   WqT 4194304 | WkT 1048576 | WvT 1048576 | WoT 4194304  = 60 MiB.
  // xb (bf16 copy of x, QN elems) ALIASES obuf: x is consumed by the QKV
  // GEMM, which completes before attention writes obuf (stream-ordered).
  const size_t QN = QN_;
  const size_t KN = KN_;
  const size_t WQT = (size_t)HID_ * (H_ * D_);     // 4194304
  const size_t WKT = (size_t)HID_ * (KVH_ * D_);   // 1048576
  const size_t need = (2 * QN + 2 * KN + 2 * WQT + 2 * WKT) * sizeof(u16);
  if (ws_size < need) {
    zero_out_k<<<(out_size + 255) / 256, 256, 0, stream>>>(out, out_size);
    return;
  }

  u16* qbuf  = (u16*)d_ws;
  u16* kbuf  = qbuf + QN;
  u16* vbufT = kbuf + KN;    // V^T: [b][kvh][d][t]
  u16* obuf  = vbufT + KN;
  u16* xb    = obuf;         // alias (see above)
  u16* WqT   = obuf + QN;    // WqT|WkT|WvT contiguous => fused-QKV WT[3072][K]
  u16* WkT   = WqT + WQT;
  u16* WvT   = WkT + WKT;
  u16* WoT   = WvT + WKT;

  const int M = B_ * T_;  // 4096
  dim3 blk(256);

  // One-time weight transposes (W[K][N] -> WT[N][K] bf16).
  transp_k<<<dim3((H_ * D_) / 64, HID_ / 64), blk, 0, stream>>>(
      Wq, WqT, HID_, H_ * D_);
  transp_k<<<dim3((KVH_ * D_) / 64, HID_ / 64), blk, 0, stream>>>(
      Wk, WkT, HID_, KVH_ * D_);
  transp_k<<<dim3((KVH_ * D_) / 64, HID_ / 64), blk, 0, stream>>>(
      Wv, WvT, HID_, KVH_ * D_);
  transp_k<<<dim3(HID_ / 64, (H_ * D_) / 64), blk, 0, stream>>>(
      Wo, WoT, H_ * D_, HID_);

  // Activation convert: x -> bf16 (xb), one pass.
  conv_bf16<<<(int)(QN / 8 / 256), blk, 0, stream>>>(x, xb, (int)(QN / 8));

  // Fused QKV projection: N = 2048(Q) + 512(K) + 512(V^T), one GEMM.
  gemm_mfma<3><<<dim3(3072 / 128, M / 128), dim3(512), 0, stream>>>(
      xb, WqT, qbuf, M, 3072, HID_);

  // RoPE. Q additionally pre-scaled by 1/sqrt(D) (folds attn scale).
  const int totq = B_ * T_ * H_ * (D_ / 2);   // 4194304
  rope_bf<<<totq / 256, blk, 0, stream>>>(qbuf, cosT, sinT, H_, totq,
                                          0.08838834764831845f);
  const int totk = B_ * T_ * KVH_ * (D_ / 2); // 1048576
  rope_bf<<<totk / 256, blk, 0, stream>>>(kbuf, cosT, sinT, KVH_, totk, 1.0f);

  // MFMA flash attention v4 (swapped QK^T, lane-local softmax).
  attn_mfma<<<dim3(B_ * H_, 16), dim3(512), 0, stream>>>(
      qbuf, kbuf, vbufT, obuf);

  // Output projection (MFMA, fp32 out).
  gemm_mfma<0><<<dim3(HID_ / 128, M / 128), dim3(512), 0, stream>>>(
      obuf, WoT, out, M, HID_, H_ * D_);
}

// Round 9
// 305.434 us; speedup vs baseline: 1.0891x; 1.0820x over previous
//
#include <hip/hip_runtime.h>
#include <hip/hip_bf16.h>

#define B_   2
#define T_   2048
#define HID_ 2048
#define H_   16
#define KVH_ 4
#define D_   128
#define GQ_  (H_ / KVH_)

#define QN_  8388608   // B*T*H*D
#define KN_  2097152   // B*T*KVH*D
#define TOTQ_ 4194304  // B*T*H*D/2  (rope q pairs)
#define TOTK_ 1048576  // B*T*KVH*D/2

typedef unsigned short u16;
typedef __attribute__((ext_vector_type(8))) unsigned short us8v;
typedef __attribute__((ext_vector_type(8))) short s16x8;   // MFMA A/B frag
typedef __attribute__((ext_vector_type(4))) float f32x4;   // MFMA C/D frag

__device__ __forceinline__ float bf2f(u16 u) {
  return __uint_as_float(((unsigned)u) << 16);
}
__device__ __forceinline__ u16 f2bf(float f) {
  unsigned x = __float_as_uint(f);
  return (u16)((x + 0x7fffu + ((x >> 16) & 1u)) >> 16);  // RNE
}

// global(16B per lane) -> LDS direct, wave-uniform dst base + lane*16.
__device__ __forceinline__ void gl2lds(const void* gp, void* lp) {
  __builtin_amdgcn_global_load_lds(
      (const __attribute__((address_space(1))) unsigned int*)gp,
      (__attribute__((address_space(3))) unsigned int*)lp, 16, 0, 0);
}

// ---------------------------------------------------------------------------
// On-device dtype probe (bf16 vs fp32), per tensor.
// ---------------------------------------------------------------------------
__device__ __forceinline__ void probe2(const void* A, const void* W, int tid,
                                       bool* abf, bool* wbf) {
  __shared__ int cA, zA, cW, zW;
  if (tid == 0) { cA = 0; zA = 0; cW = 0; zW = 0; }
  __syncthreads();
  const int i = 16384 + tid;
  {
    const u16 raw = ((const u16*)A)[i];
    const float v = bf2f(raw);
    const bool bad = !(fabsf(v) <= 1e6f) ||
                     (v != 0.0f && fabsf(v) < 1e-10f);
    if (bad) atomicAdd(&cA, 1);
    if (((tid & 1) == 0) && raw == 0) atomicAdd(&zA, 1);
  }
  {
    const u16 raw = ((const u16*)W)[i];
    const float v = bf2f(raw);
    const bool bad = !(fabsf(v) <= 1e6f) ||
                     (v != 0.0f && fabsf(v) < 1e-10f);
    if (bad) atomicAdd(&cW, 1);
    if (((tid & 1) == 0) && raw == 0) atomicAdd(&zW, 1);
  }
  __syncthreads();
  *abf = (cA < 8) && (zA < 100);
  *wbf = (cW < 8) && (zW < 100);
}

// ---------------------------------------------------------------------------
// Transpose body: W[K][N] (bf16 OR fp32, probed) -> WT[N][K] bf16.
// ---------------------------------------------------------------------------
__device__ void transp_body(const void* __restrict__ Wv_,
                            u16* __restrict__ WT, int K, int N, int bx,
                            int by, int tid) {
  bool wbf, dummy;
  probe2(Wv_, Wv_, tid, &wbf, &dummy);

  __shared__ float tile[64][65];
  const int kb = by * 64;
  const int nb = bx * 64;

  for (int it = tid; it < 512; it += 256) {
    const int r = it >> 3;
    const int g = it & 7;
    const size_t off = (size_t)(kb + r) * N + nb + g * 8;
    float f[8];
    if (wbf) {
      const us8v t8 = *(const us8v*)((const u16*)Wv_ + off);
#pragma unroll
      for (int e = 0; e < 8; ++e) f[e] = bf2f(t8[e]);
    } else {
      const float4 f0 = *(const float4*)((const float*)Wv_ + off);
      const float4 f1 = *(const float4*)((const float*)Wv_ + off + 4);
      f[0] = f0.x; f[1] = f0.y; f[2] = f0.z; f[3] = f0.w;
      f[4] = f1.x; f[5] = f1.y; f[6] = f1.z; f[7] = f1.w;
    }
#pragma unroll
    for (int e = 0; e < 8; ++e) tile[r][g * 8 + e] = f[e];
  }
  __syncthreads();
  for (int it = tid; it < 512; it += 256) {
    const int n = it >> 3;
    const int g = it & 7;
    us8v tmp;
#pragma unroll
    for (int e = 0; e < 8; ++e) tmp[e] = f2bf(tile[g * 8 + e][n]);
    *(us8v*)&WT[(size_t)(nb + n) * K + kb + g * 8] = tmp;
  }
}

// ---------------------------------------------------------------------------
// Activation-convert body: x (fp32 OR bf16, probed) -> bf16, 8 elems/thread.
// ---------------------------------------------------------------------------
__device__ void conv_body(const void* __restrict__ in, u16* __restrict__ outb,
                          int cb, int tid) {
  bool ibf, dummy;
  probe2(in, in, tid, &ibf, &dummy);
  const int idx = cb * 256 + tid;
  if (idx >= (QN_ / 8)) return;
  if (ibf) {
    *(us8v*)&outb[(size_t)idx * 8] =
        *(const us8v*)((const u16*)in + (size_t)idx * 8);
  } else {
    const float4 f0 = *(const float4*)((const float*)in + (size_t)idx * 8);
    const float4 f1 = *(const float4*)((const float*)in + (size_t)idx * 8 + 4);
    uint4 w;
    asm("v_cvt_pk_bf16_f32 %0, %1, %2" : "=v"(w.x) : "v"(f0.x), "v"(f0.y));
    asm("v_cvt_pk_bf16_f32 %0, %1, %2" : "=v"(w.y) : "v"(f0.z), "v"(f0.w));
    asm("v_cvt_pk_bf16_f32 %0, %1, %2" : "=v"(w.z) : "v"(f1.x), "v"(f1.y));
    asm("v_cvt_pk_bf16_f32 %0, %1, %2" : "=v"(w.w) : "v"(f1.z), "v"(f1.w));
    *(uint4*)&outb[(size_t)idx * 8] = w;
  }
}

// ---------------------------------------------------------------------------
// Fused prep: all 4 weight transposes + x->bf16 convert in ONE dispatch
// (blockIdx-range dispatch; compile-time per-range geometry). Cuts 4
// launch gaps.  Ranges: [0,1024) Wq | [1024,1280) Wk | [1280,1536) Wv |
// [1536,2560) Wo | [2560,6656) conv.
// ---------------------------------------------------------------------------
__global__ __launch_bounds__(256) void prep_k(
    const void* __restrict__ Wq, const void* __restrict__ Wk,
    const void* __restrict__ Wv, const void* __restrict__ Wo,
    const void* __restrict__ x, u16* __restrict__ WqT,
    u16* __restrict__ WkT, u16* __restrict__ WvT, u16* __restrict__ WoT,
    u16* __restrict__ xb) {
  const int b = blockIdx.x;
  const int tid = threadIdx.x;
  if (b < 1024) {
    transp_body(Wq, WqT, HID_, H_ * D_, b & 31, b >> 5, tid);
  } else if (b < 1280) {
    const int bb = b - 1024;
    transp_body(Wk, WkT, HID_, KVH_ * D_, bb & 7, bb >> 3, tid);
  } else if (b < 1536) {
    const int bb = b - 1280;
    transp_body(Wv, WvT, HID_, KVH_ * D_, bb & 7, bb >> 3, tid);
  } else if (b < 2560) {
    const int bb = b - 1536;
    transp_body(Wo, WoT, H_ * D_, HID_, bb & 31, bb >> 5, tid);
  } else {
    conv_body(x, xb, b - 2560, tid);
  }
}

// ---------------------------------------------------------------------------
// MFMA GEMM v5: C[M,N] = A[M,K] @ W[K,N]; A bf16, WT[N][K] bf16.
// 128xBN tile (BN=192 QKV exact 512-block grid, BN=128 Wo), BK=64
// (halves barrier windows: R6/R7/R8 all pinned at 75us/28% MfmaUtil ->
// probing whether per-window overhead is fixed (then this wins) or
// proportional/2-phase-structural (then flat -> next round = 8-phase port).
// 8 waves (2M x 4N), dbuf, one __syncthreads per 64-k step.
// Swizzle for 64-elem rows: granule gs = g ^ (r&7) folded into global
// source; frag read granule (ks*4+lq) ^ (row&7) -> per-bank word count
// uniform (8/bank = b128 minimum) for staging AND reads.
// OMODE: 0 = fp32 out; 3 = fused QKV epilogue (qbuf/kbuf/vT split).
// ---------------------------------------------------------------------------
template <int OMODE, int BN>
__global__ __launch_bounds__(512, 4) void gemm_mfma(
    const u16* __restrict__ Ab, const u16* __restrict__ WT,
    void* __restrict__ Cv, int M, int N, int K) {
  const int tid = threadIdx.x;

  __shared__ __align__(16) u16 Alds[2][128 * 64];
  __shared__ __align__(16) u16 Blds[2][BN * 64];

  const int m0 = blockIdx.y * 128;
  const int n0 = blockIdx.x * BN;
  const int wave = tid >> 6;               // 0..7
  const int lane = tid & 63;
  const int wm = (wave >> 2) * 64;         // 2 m-halves
  const int wn = (wave & 3) * (BN / 4);    // 4 n-slices
  const int lrow = lane & 15;
  const int lq = lane >> 4;
  constexpr int NI = BN / 64;              // n-frags per wave (3 or 2)

  f32x4 acc[4][NI] = {};

#define G_STAGE64(bi, kk)                                                     \
  do {                                                                        \
    _Pragma("unroll") for (int _p = 0; _p < 2; ++_p) {                        \
      const int _it = tid + _p * 512;                                         \
      const int _r = _it >> 3, _g = _it & 7;                                  \
      const int _gs = _g ^ (_r & 7);                                          \
      gl2lds(Ab + (size_t)(m0 + _r) * K + (kk) + _gs * 8,                     \
             &Alds[bi][((tid & ~63) + _p * 512) * 8]);                        \
    }                                                                         \
    _Pragma("unroll") for (int _p = 0; _p < (BN / 64); ++_p) {                \
      const int _it = tid + _p * 512;                                         \
      const int _n = _it >> 3, _g = _it & 7;                                  \
      const int _gs = _g ^ (_n & 7);                                          \
      gl2lds(WT + (size_t)(n0 + _n) * K + (kk) + _gs * 8,                     \
             &Blds[bi][((tid & ~63) + _p * 512) * 8]);                        \
    }                                                                         \
  } while (0)

  G_STAGE64(0, 0);
  __syncthreads();  // drains vmcnt: buf0 ready

  int cur = 0;
  for (int k0 = 0; k0 < K; k0 += 64) {
    if (k0 + 64 < K) G_STAGE64(cur ^ 1, k0 + 64);

#pragma unroll
    for (int ks = 0; ks < 2; ++ks) {
      s16x8 af[4], bfr[NI];
#pragma unroll
      for (int mi = 0; mi < 4; ++mi) {
        const int row = wm + 16 * mi + lrow;
        af[mi] = *(const s16x8*)&Alds[cur][row * 64 +
                                           (((ks * 4 + lq) ^ (row & 7)) * 8)];
      }
#pragma unroll
      for (int ni = 0; ni < NI; ++ni) {
        const int row = wn + 16 * ni + lrow;
        bfr[ni] = *(const s16x8*)&Blds[cur][row * 64 +
                                            (((ks * 4 + lq) ^ (row & 7)) * 8)];
      }
      __builtin_amdgcn_s_setprio(1);
#pragma unroll
      for (int mi = 0; mi < 4; ++mi)
#pragma unroll
        for (int ni = 0; ni < NI; ++ni)
          acc[mi][ni] = __builtin_amdgcn_mfma_f32_16x16x32_bf16(
              af[mi], bfr[ni], acc[mi][ni], 0, 0, 0);
      __builtin_amdgcn_s_setprio(0);
    }

    __syncthreads();  // drains vmcnt: buf^1 staged; buf[cur] reads retired
    cur ^= 1;
  }
#undef G_STAGE64

  // epilogue: D col=lane&15, row=quad*4+reg
#pragma unroll
  for (int mi = 0; mi < 4; ++mi) {
#pragma unroll
    for (int ni = 0; ni < NI; ++ni) {
      const int row0 = m0 + wm + 16 * mi + lq * 4;
      const int col = n0 + wn + 16 * ni + lrow;
#pragma unroll
      for (int r = 0; r < 4; ++r) {
        const int row = row0 + r;
        if (OMODE == 0) {
          ((float*)Cv)[(size_t)row * N + col] = acc[mi][ni][r];
        } else {
          const u16 val = f2bf(acc[mi][ni][r]);
          if (col < 2048) {
            ((u16*)Cv)[(size_t)row * 2048 + col] = val;           // qbuf
          } else if (col < 2560) {
            ((u16*)Cv)[QN_ + (size_t)row * 512 + (col - 2048)] = val;  // kbuf
          } else {
            const int c = col - 2560;          // 0..511
            const int kvh = c >> 7;
            const int d = c & 127;
            const int bb = row >> 11;          // T_ == 2048
            const int tt = row & (T_ - 1);
            ((u16*)Cv)[QN_ + KN_ +
                       ((size_t)(bb * KVH_ + kvh) * D_ + d) * T_ + tt] = val;
          }
        }
      }
    }
  }
}

// ---------------------------------------------------------------------------
// Fused RoPE (Q and K in one dispatch). Q pre-scaled by 1/sqrt(D).
// ---------------------------------------------------------------------------
__global__ __launch_bounds__(256) void rope2(u16* __restrict__ qb,
                                             u16* __restrict__ kb,
                                             const void* __restrict__ cosT,
                                             const void* __restrict__ sinT) {
  const int tid = threadIdx.x;
  bool cbf, sbf;
  probe2(cosT, sinT, tid, &cbf, &sbf);

  int idx = blockIdx.x * 256 + tid;
  u16* t;
  int NH;
  float qs;
  if (idx < TOTQ_) {
    t = qb; NH = H_; qs = 0.08838834764831845f;
  } else {
    idx -= TOTQ_;
    if (idx >= TOTK_) return;
    t = kb; NH = KVH_; qs = 1.0f;
  }
  const int d = idx & 63;
  const int rest = idx >> 6;
  const int tt = (rest / NH) % T_;
  const size_t base = (size_t)rest * D_;
  const int ci = tt * D_ + d;
  float c1, s1, c2, s2;
  if (cbf) {
    c1 = bf2f(((const u16*)cosT)[ci]);
    c2 = bf2f(((const u16*)cosT)[ci + 64]);
  } else {
    c1 = ((const float*)cosT)[ci];
    c2 = ((const float*)cosT)[ci + 64];
  }
  if (sbf) {
    s1 = bf2f(((const u16*)sinT)[ci]);
    s2 = bf2f(((const u16*)sinT)[ci + 64]);
  } else {
    s1 = ((const float*)sinT)[ci];
    s2 = ((const float*)sinT)[ci + 64];
  }
  const float x1 = bf2f(t[base + d]);
  const float x2 = bf2f(t[base + d + 64]);
  t[base + d] = f2bf((x1 * c1 - x2 * s1) * qs);
  t[base + d + 64] = f2bf((x2 * c2 + x1 * s2) * qs);
}

// ---------------------------------------------------------------------------
// Causal GQA flash attention, MFMA v4 (unchanged, passing):
// swapped QK^T (lane-local softmax), paired q-tiles, 8 waves, dbuf
// global_load_lds staging, defer-max, setprio.
// ---------------------------------------------------------------------------
#define ATT_STAGE(bi, ktile)                                                  \
  do {                                                                        \
    const int _k0 = (ktile) * 64;                                             \
    u16* _bk = &SM[(bi) * 16384];                                             \
    _Pragma("unroll") for (int _p = 0; _p < 2; ++_p) {                        \
      const int _it = tid + _p * 512;                                         \
      const int _r = _it >> 4, _s = _it & 15;                                 \
      gl2lds(kp + (size_t)(_k0 + _r) * (KVH_ * D_) + ((_s ^ (_r & 7)) * 8),   \
             &_bk[((tid & ~63) + _p * 512) * 8]);                             \
    }                                                                         \
    _Pragma("unroll") for (int _p = 0; _p < 2; ++_p) {                        \
      const int _it = tid + _p * 512;                                         \
      const int _r = _it >> 3, _s = _it & 7;                                  \
      gl2lds(vp + (size_t)_r * T_ + _k0 + ((_s ^ (_r & 7)) * 8),              \
             &_bk[8192 + ((tid & ~63) + _p * 512) * 8]);                      \
    }                                                                         \
  } while (0)

__global__ __launch_bounds__(512, 4) void attn_mfma(
    const u16* __restrict__ q, const u16* __restrict__ k,
    const u16* __restrict__ vT, u16* __restrict__ o) {
  const int tid = threadIdx.x;
  const int ip = blockIdx.y;                 // pair index 0..15
  const int bh = blockIdx.x;
  const int b = bh >> 4;
  const int h = bh & 15;
  const int kvh = h >> 2;
  const int hi0 = 64 * (31 - ip);
  const int lo0 = 64 * ip;

  __shared__ __align__(16) u16 SM[2 * 16384];  // dbuf {Ks 64x128, Vt 128x64}
  __shared__ __align__(16) u16 Pl[128 * 64];   // P (bf16), granule-XOR

  const int wave = tid >> 6;                 // 0..7
  const int lane = tid & 63;
  const int l15 = lane & 15;
  const int quad = lane >> 4;
  const bool isHi = wave < 4;
  const int rowbase = isHi ? (hi0 + 16 * wave) : (lo0 + 16 * (wave - 4));
  const int pr0 = 16 * wave;                 // Pl row base, wave-private

  const u16* kp = k + ((size_t)b * T_ * KVH_ + kvh) * D_;
  const u16* vp = vT + (size_t)(b * KVH_ + kvh) * D_ * T_;

  // Q fragment, reg-resident: B-layout [n=q=l15][d=st*32+quad*8+j].
  s16x8 qf[4];
  {
    const size_t qrow = ((size_t)(b * T_ + rowbase + l15) * H_ + h) * D_;
#pragma unroll
    for (int st = 0; st < 4; ++st)
      qf[st] = *(const s16x8*)&q[qrow + st * 32 + quad * 8];
  }

  f32x4 acc_o[8] = {};   // PV out: row q=quad*4+r, col d=nt2*16+l15
  float m_s = -1.0e30f, l_s = 0.0f;   // per-lane state for q = rowbase+l15

  const int nkt = 32 - ip;  // hi tile count; lo active while kt <= ip

  ATT_STAGE(0, 0);
  __syncthreads();

  for (int kt = 0; kt < nkt; ++kt) {
    const int k0 = kt * 64;
    const u16* Ks = &SM[(kt & 1) * 16384];
    const u16* Vt = Ks + 8192;

    if (kt + 1 < nkt) ATT_STAGE((kt + 1) & 1, kt + 1);

    const bool active = isHi || (kt <= ip);  // wave-uniform
    if (active) {
      // ---- swapped QK^T: lane holds S[q=l15][k=nt*16+quad*4+r] ----
      f32x4 accs[4] = {};
      __builtin_amdgcn_s_setprio(1);
#pragma unroll
      for (int st = 0; st < 4; ++st) {
        const int g = st * 4 + quad;
#pragma unroll
        for (int nt = 0; nt < 4; ++nt) {
          const int row = nt * 16 + l15;
          const s16x8 kf =
              *(const s16x8*)&Ks[row * 128 + ((g ^ (row & 7)) << 3)];
          accs[nt] = __builtin_amdgcn_mfma_f32_16x16x32_bf16(kf, qf[st],
                                                             accs[nt], 0, 0,
                                                             0);
        }
      }
      __builtin_amdgcn_s_setprio(0);

      // ---- causal mask: wave-uniform branch, rare ----
      if ((k0 + 63) > rowbase) {
        const int qg = rowbase + l15;
#pragma unroll
        for (int nt = 0; nt < 4; ++nt)
#pragma unroll
          for (int r = 0; r < 4; ++r)
            if (qg < (k0 + nt * 16 + quad * 4 + r)) accs[nt][r] = -1.0e30f;
      }

      // ---- row max: in-lane tree + 2 shfl ----
      float t0 = fmaxf(fmaxf(accs[0][0], accs[0][1]),
                       fmaxf(accs[0][2], accs[0][3]));
      float t1 = fmaxf(fmaxf(accs[1][0], accs[1][1]),
                       fmaxf(accs[1][2], accs[1][3]));
      float t2 = fmaxf(fmaxf(accs[2][0], accs[2][1]),
                       fmaxf(accs[2][2], accs[2][3]));
      float t3 = fmaxf(fmaxf(accs[3][0], accs[3][1]),
                       fmaxf(accs[3][2], accs[3][3]));
      float mx = fmaxf(fmaxf(t0, t1), fmaxf(t2, t3));
      mx = fmaxf(mx, __shfl_xor(mx, 16));
      mx = fmaxf(mx, __shfl_xor(mx, 32));

      // ---- defer-max (T13) ----
      const int defer = __all(mx <= m_s + 8.0f);
      float alv = 1.0f;
      if (!defer) {
        const float mnew = fmaxf(m_s, mx);
        alv = __expf(m_s - mnew);
        m_s = mnew;
      }

      // ---- exp ----
#pragma unroll
      for (int nt = 0; nt < 4; ++nt)
#pragma unroll
        for (int r = 0; r < 4; ++r)
          accs[nt][r] = __expf(accs[nt][r] - m_s);

      // ---- pack + write P early (ds latency overlaps the sum) ----
#pragma unroll
      for (int nt = 0; nt < 4; ++nt) {
        uint2 w;
        asm("v_cvt_pk_bf16_f32 %0, %1, %2"
            : "=v"(w.x) : "v"(accs[nt][0]), "v"(accs[nt][1]));
        asm("v_cvt_pk_bf16_f32 %0, %1, %2"
            : "=v"(w.y) : "v"(accs[nt][2]), "v"(accs[nt][3]));
        const int prow = pr0 + l15;
        const int c0 = nt * 16 + quad * 4;
        *(uint2*)&Pl[prow * 64 + (((c0 >> 3) ^ (prow & 7)) << 3) + (c0 & 7)] =
            w;
      }

      // ---- row sum + state update ----
      float s0 = (accs[0][0] + accs[0][1]) + (accs[0][2] + accs[0][3]);
      float s1 = (accs[1][0] + accs[1][1]) + (accs[1][2] + accs[1][3]);
      float s2 = (accs[2][0] + accs[2][1]) + (accs[2][2] + accs[2][3]);
      float s3 = (accs[3][0] + accs[3][1]) + (accs[3][2] + accs[3][3]);
      float rs = (s0 + s1) + (s2 + s3);
      rs += __shfl_xor(rs, 16);
      rs += __shfl_xor(rs, 32);
      l_s = l_s * alv + rs;

      // ---- O rescale (only when max grew; al redistributed to PV rows) ----
      if (!defer) {
#pragma unroll
        for (int r = 0; r < 4; ++r) {
          const float a4 = __shfl(alv, 4 * quad + r);
#pragma unroll
          for (int nt2 = 0; nt2 < 8; ++nt2) acc_o[nt2][r] *= a4;
        }
      }

      asm volatile("s_waitcnt lgkmcnt(0)" ::: "memory");
      __builtin_amdgcn_sched_barrier(0);

      // ---- PV: O[16q x 128d] += P[16x64] @ V[64x128] ----
      s16x8 pa[2];
#pragma unroll
      for (int ks = 0; ks < 2; ++ks) {
        const int row = pr0 + l15;
        const int g = ks * 4 + quad;
        pa[ks] = *(const s16x8*)&Pl[row * 64 + ((g ^ (row & 7)) << 3)];
      }
      __builtin_amdgcn_s_setprio(1);
#pragma unroll
      for (int ks = 0; ks < 2; ++ks) {
        const int g = ks * 4 + quad;
#pragma unroll
        for (int nt2 = 0; nt2 < 8; ++nt2) {
          const int row = nt2 * 16 + l15;
          const s16x8 vf =
              *(const s16x8*)&Vt[row * 64 + ((g ^ (row & 7)) << 3)];
          acc_o[nt2] = __builtin_amdgcn_mfma_f32_16x16x32_bf16(pa[ks], vf,
                                                               acc_o[nt2], 0,
                                                               0, 0);
        }
      }
      __builtin_amdgcn_s_setprio(0);
    }

    __syncthreads();  // drains vmcnt: buf^1 staged; all LDS reads retired
  }

  // ---- epilogue: normalize + store (linv redistributed to PV rows) ----
  const float inv = 1.0f / l_s;
#pragma unroll
  for (int r = 0; r < 4; ++r) {
    const float linv = __shfl(inv, 4 * quad + r);
    const size_t orow =
        ((size_t)(b * T_ + rowbase + quad * 4 + r) * H_ + h) * D_;
#pragma unroll
    for (int nt2 = 0; nt2 < 8; ++nt2)
      o[orow + nt2 * 16 + l15] = f2bf(acc_o[nt2][r] * linv);
  }
}

// Fallback: zero d_out (fp32) so an undersized workspace fails cleanly.
__global__ void zero_out_k(float* __restrict__ out, int n) {
  const int i = blockIdx.x * blockDim.x + threadIdx.x;
  if (i < n) out[i] = 0.0f;
}

// ---------------------------------------------------------------------------
extern "C" void kernel_launch(void* const* d_in, const int* in_sizes, int n_in,
                              void* d_out, int out_size, void* d_ws,
                              size_t ws_size, hipStream_t stream) {
  const void* x    = d_in[0];
  const void* cosT = d_in[1];
  const void* sinT = d_in[2];
  const void* Wq   = d_in[3];
  const void* Wk   = d_in[4];
  const void* Wv   = d_in[5];
  const void* Wo   = d_in[6];
  float* out = (float*)d_out;

  // Workspace (bf16 elems): qbuf QN | kbuf KN | vbufT KN | obuf QN |
  //   WqT 4194304 | WkT 1048576 | WvT 1048576 | WoT 4194304  = 60 MiB.
  // xb (bf16 copy of x, QN elems) ALIASES obuf: x is consumed by the QKV
  // GEMM, which completes before attention writes obuf (stream-ordered).
  const size_t QN = QN_;
  const size_t KN = KN_;
  const size_t WQT = (size_t)HID_ * (H_ * D_);     // 4194304
  const size_t WKT = (size_t)HID_ * (KVH_ * D_);   // 1048576
  const size_t need = (2 * QN + 2 * KN + 2 * WQT + 2 * WKT) * sizeof(u16);
  if (ws_size < need) {
    zero_out_k<<<(out_size + 255) / 256, 256, 0, stream>>>(out, out_size);
    return;
  }

  u16* qbuf  = (u16*)d_ws;
  u16* kbuf  = qbuf + QN;
  u16* vbufT = kbuf + KN;    // V^T: [b][kvh][d][t]
  u16* obuf  = vbufT + KN;
  u16* xb    = obuf;         // alias (see above)
  u16* WqT   = obuf + QN;    // WqT|WkT|WvT contiguous => fused-QKV WT[3072][K]
  u16* WkT   = WqT + WQT;
  u16* WvT   = WkT + WKT;
  u16* WoT   = WvT + WKT;

  const int M = B_ * T_;  // 4096

  // 1) Fused prep: 4 transposes + x->bf16 (one dispatch).
  prep_k<<<6656, 256, 0, stream>>>(Wq, Wk, Wv, Wo, x, WqT, WkT, WvT, WoT, xb);

  // 2) Fused QKV projection: N = 2048(Q)+512(K)+512(V^T). BN=192 -> grid
  //    16x32 = 512 blocks = exactly 2/CU.
  gemm_mfma<3, 192><<<dim3(3072 / 192, M / 128), dim3(512), 0, stream>>>(
      xb, WqT, qbuf, M, 3072, HID_);

  // 3) Fused RoPE (Q scaled by 1/sqrt(D), K unscaled) — one dispatch.
  rope2<<<(TOTQ_ + TOTK_) / 256, 256, 0, stream>>>(qbuf, kbuf, cosT, sinT);

  // 4) MFMA flash attention v4 (swapped QK^T, lane-local softmax).
  attn_mfma<<<dim3(B_ * H_, 16), dim3(512), 0, stream>>>(
      qbuf, kbuf, vbufT, obuf);

  // 5) Output projection (fp32 out). BN=128 -> grid 16x32 = 512 blocks.
  gemm_mfma<0, 128><<<dim3(HID_ / 128, M / 128), dim3(512), 0, stream>>>(
      obuf, WoT, out, M, HID_, H_ * D_);
}